// Round 18
// baseline (105.105 us; speedup 1.0000x reference)
//
#include <hip/hip_runtime.h>

#define N_NODES 100000
#define N_EDGES 600000
#define D 128
#define M_PAD 100096            // allocation pad for AbufN rows

#define NB   196                // buckets = tgt >> 9
#define BWID 512                // nodes per bucket
#define NCH  196                // edge chunks
#define CE   3062               // edges per chunk (last: 2910)
#define SCAN_N (NB * NCH)       // 38416
#define SCAN_BLK 151            // ceil(SCAN_N / 256)

typedef unsigned int uint32;
typedef unsigned long long uint64;
typedef __attribute__((ext_vector_type(8))) short short8;
typedef __attribute__((ext_vector_type(4))) float f32x4;

__device__ __forceinline__ uint32 f2bf(float x) {          // RNE f32 -> bf16
    uint32 u = __float_as_uint(x);
    return (u + 0x7FFFu + ((u >> 16) & 1u)) >> 16;
}
__device__ __forceinline__ float bflo(uint32 u) { return __uint_as_float(u << 16); }
__device__ __forceinline__ float bfhi(uint32 u) { return __uint_as_float(u & 0xFFFF0000u); }

// ---------------------------------------------------------------------------
// K1: convert nf -> bf16 compact AbufN[r][128] (grid-stride, 1024 blocks);
// blocks 0..195 also count their edge-chunk's bucket histogram in LDS.
// Block 1023 zeroes the scan flags.
// ---------------------------------------------------------------------------
__global__ __launch_bounds__(256) void k1_convert_count(
        const float* __restrict__ nf, unsigned short* __restrict__ AbufN,
        const int* __restrict__ edges, uint32* __restrict__ cntmat,
        uint64* __restrict__ flags) {
    __shared__ uint32 c[NB];
    const int tid = threadIdx.x;
    const int bid = blockIdx.x;

    if (bid == 1023 && tid < SCAN_BLK) flags[tid] = 0ULL;

    for (int idx = bid * 256 + tid; idx < N_NODES * 16; idx += 1024 * 256) {
        int r = idx >> 4;
        int ccol = (idx & 15) * 8;
        const float4 v0 = *reinterpret_cast<const float4*>(nf + (size_t)r * D + ccol);
        const float4 v1 = *reinterpret_cast<const float4*>(nf + (size_t)r * D + ccol + 4);
        uint4 w;
        w.x = f2bf(v0.x) | (f2bf(v0.y) << 16);
        w.y = f2bf(v0.z) | (f2bf(v0.w) << 16);
        w.z = f2bf(v1.x) | (f2bf(v1.y) << 16);
        w.w = f2bf(v1.z) | (f2bf(v1.w) << 16);
        *reinterpret_cast<uint4*>(AbufN + (size_t)r * 128 + ccol) = w;
    }

    if (bid < NCH) {
        for (int i = tid; i < NB; i += 256) c[i] = 0u;
        __syncthreads();
        const int e0 = bid * CE;
        const int e1 = (e0 + CE < N_EDGES) ? e0 + CE : N_EDGES;
        for (int e = e0 + tid; e < e1; e += 256) {
            int tgt = edges[N_EDGES + e];
            atomicAdd(&c[tgt >> 9], 1u);               // LDS atomic
        }
        __syncthreads();
        for (int i = tid; i < NB; i += 256)
            cntmat[(size_t)i * NCH + bid] = c[i];      // bucket-major
    }
}

// ---------------------------------------------------------------------------
// K2: publish/poll exclusive scan over cntmat (38416 elems, 151 blocks),
// in-place counts -> bases. Idle width does W-prep + bias fuse.
// ---------------------------------------------------------------------------
__global__ __launch_bounds__(256) void k2_scan(
        uint32* __restrict__ cntmat, uint64* __restrict__ flags,
        const float* __restrict__ Wl, const float* __restrict__ Ws,
        const float* __restrict__ bl, const float* __restrict__ bs,
        unsigned short* __restrict__ WcF, float* __restrict__ biasc) {
    const int gidx = blockIdx.x * 256 + threadIdx.x;
    if (gidx < 4096) {
        int lane = gidx & 63, f2 = gidx >> 6;
        int ks = f2 & 7, nn = (f2 >> 3) & 3, ch = f2 >> 5;
        int j = ch * 64 + nn * 16 + (lane & 15);
        int kb = ks * 32 + (lane >> 4) * 8;
        const float* srcp = (kb < D) ? (Wl + (size_t)j * D + kb)
                                     : (Ws + (size_t)j * D + (kb - D));
        const float4 v0 = *reinterpret_cast<const float4*>(srcp);
        const float4 v1 = *reinterpret_cast<const float4*>(srcp + 4);
        uint4 w;
        w.x = f2bf(v0.x) | (f2bf(v0.y) << 16);
        w.y = f2bf(v0.z) | (f2bf(v0.w) << 16);
        w.z = f2bf(v1.x) | (f2bf(v1.y) << 16);
        w.w = f2bf(v1.z) | (f2bf(v1.w) << 16);
        *reinterpret_cast<uint4*>(WcF + (size_t)gidx * 8) = w;
    }
    if (gidx < D) biasc[gidx] = bl[gidx] + bs[gidx];

    __shared__ uint32 s[256];
    __shared__ uint32 r2[256];
    const int t = threadIdx.x;
    const int b = blockIdx.x;
    const int i = b * 256 + t;
    const uint32 v = (i < SCAN_N) ? cntmat[i] : 0u;
    s[t] = v;
    __syncthreads();
    for (int d = 1; d < 256; d <<= 1) {
        uint32 add = (t >= d) ? s[t - d] : 0u;
        __syncthreads();
        s[t] += add;
        __syncthreads();
    }
    const uint32 incl = s[t];
    const uint32 total = s[255];
    if (t == 0) atomicExch(&flags[b], (1ULL << 32) | (uint64)total);
    uint32 agg = 0;
    if (t < b) {                                       // b <= 150 < 256
        uint64 fv;
        do { fv = atomicAdd(&flags[t], 0ULL); } while ((fv >> 32) == 0ULL);
        agg = (uint32)fv;
    }
    r2[t] = agg;
    __syncthreads();
    for (int d2 = 128; d2 > 0; d2 >>= 1) {
        if (t < d2) r2[t] += r2[t + d2];
        __syncthreads();
    }
    if (i < SCAN_N) cntmat[i] = r2[0] + incl - v;      // exclusive base, in place
}

// ---------------------------------------------------------------------------
// K3: scatter edges into bucket-grouped PACKED array ((tgt&511)<<17 | src).
// Rank via LDS atomic return + disjoint (bucket,chunk) bases -> no g-atomics.
// ---------------------------------------------------------------------------
__global__ __launch_bounds__(256) void k3_bucket(
        const int* __restrict__ edges, const uint32* __restrict__ base,
        uint32* __restrict__ bpair) {
    __shared__ uint32 c[NB];
    __shared__ uint32 bb[NB];
    const int t = threadIdx.x;
    const int cid = blockIdx.x;
    for (int i = t; i < NB; i += 256) {
        c[i] = 0u;
        bb[i] = base[(size_t)i * NCH + cid];
    }
    __syncthreads();
    const int e0 = cid * CE;
    const int e1 = (e0 + CE < N_EDGES) ? e0 + CE : N_EDGES;
    for (int e = e0 + t; e < e1; e += 256) {
        uint32 src = (uint32)edges[e];
        uint32 tgt = (uint32)edges[N_EDGES + e];
        uint32 bkt = tgt >> 9;
        uint32 r = atomicAdd(&c[bkt], 1u);             // LDS atomic
        bpair[bb[bkt] + r] = ((tgt & 511u) << 17) | src;
    }
}

// ---------------------------------------------------------------------------
// K4: one block per bucket. LDS 512-counter histogram -> local exclusive
// scan -> off[] (+ sentinel) and sorted_src (L2-local windows).
// ---------------------------------------------------------------------------
__global__ __launch_bounds__(256) void k4_csr(
        const uint32* __restrict__ bpair, const uint32* __restrict__ base,
        uint32* __restrict__ off, uint32* __restrict__ sorted_src) {
    __shared__ uint32 h[BWID];
    __shared__ uint32 h2[BWID];
    __shared__ uint32 pr[256];
    const int t = threadIdx.x;
    const int b = blockIdx.x;
    const uint32 start = base[(size_t)b * NCH];
    const uint32 end = (b == NB - 1) ? N_EDGES : base[(size_t)(b + 1) * NCH];
    for (int i = t; i < BWID; i += 256) { h[i] = 0u; h2[i] = 0u; }
    __syncthreads();
    for (uint32 e = start + t; e < end; e += 256) {
        atomicAdd(&h[bpair[e] >> 17], 1u);             // LDS atomic
    }
    __syncthreads();
    const uint32 e0c = h[2 * t];
    const uint32 e1c = h[2 * t + 1];
    pr[t] = e0c + e1c;
    __syncthreads();
    for (int d = 1; d < 256; d <<= 1) {
        uint32 add = (t >= d) ? pr[t - d] : 0u;
        __syncthreads();
        pr[t] += add;
        __syncthreads();
    }
    const uint32 exb = (t > 0) ? pr[t - 1] : 0u;
    const int node0 = b * BWID + 2 * t;
    if (node0 < N_NODES) off[node0] = start + exb;
    if (node0 + 1 < N_NODES) off[node0 + 1] = start + exb + e0c;
    if (b == NB - 1 && t == 0) off[N_NODES] = N_EDGES;  // sentinel
    h[2 * t] = exb;
    h[2 * t + 1] = exb + e0c;
    __syncthreads();
    for (uint32 e = start + t; e < end; e += 256) {
        uint32 pq = bpair[e];
        uint32 lt = pq >> 17;
        uint32 r = atomicAdd(&h2[lt], 1u);              // LDS atomic
        sorted_src[start + h[lt] + r] = pq & 0x1FFFFu;
    }
}

// ---------------------------------------------------------------------------
// K5 fused gather + MFMA GEMM (R14 base + round-1 hoist). Block = 64 rows x
// 128 cols, 512 threads, WcL (64 KB) + Am (16 KB) in LDS -> 2 blocks/CU
// (LDS-limited -> 4 waves/SIMD -> VGPR budget ~512, no clamp). Gather:
// hoist off/deg, round-0 AND round-1 clamped indices; issue all round-0 row
// loads, then round-1 row loads ONLY for d>8 groups (exec-masked); j>=16
// loop covers the 0.02% tail. One latency round for d<=8, two for d<=16.
// ---------------------------------------------------------------------------
__global__ __launch_bounds__(512) void k_fused(
        const unsigned short* __restrict__ AbufN,
        const uint32* __restrict__ off,
        const uint32* __restrict__ sorted_src,
        const unsigned short* __restrict__ WcF,
        const float* __restrict__ biasc,
        float* __restrict__ out) {
    __shared__ unsigned short WcL[32768];       // 64 KB
    __shared__ unsigned short Am[8192];         // 16 KB: 64 x 128 bf16 (swizzled)
    const int tid = threadIdx.x;
    const int wave = tid >> 6;                  // 0..7
    const int lane = tid & 63;
    const int row0 = blockIdx.x * 64;

    // stage all W fragments (linear copy; overlaps with gather loads)
#pragma unroll
    for (int i = 0; i < 8; ++i) {
        const int o = (i * 512 + tid) * 8;
        *reinterpret_cast<short8*>(&WcL[o]) = *reinterpret_cast<const short8*>(WcF + o);
    }

    const int sub = (lane >> 4) & 1;            // edge parity
    const int cl  = lane & 15;                  // 16B column chunk
    const int g   = lane >> 5;                  // node within pair

#define LD(s) (*reinterpret_cast<const uint4*>(AbufN + (size_t)(s) * 128 + cl * 8))
#define ACC(a, u) { a[0] += bflo(u.x); a[1] += bfhi(u.x); a[2] += bflo(u.y); a[3] += bfhi(u.y); \
                    a[4] += bflo(u.z); a[5] += bfhi(u.z); a[6] += bflo(u.w); a[7] += bfhi(u.w); }

    // ---- hoisted off/deg loads: 4 pairs, 8 independent loads ----
    uint32 oo[4], dd[4];
#pragma unroll
    for (int pr2 = 0; pr2 < 4; ++pr2) {
        const int nl = wave * 8 + pr2 * 2 + g;
        const int node = row0 + nl;
        const int nn = (node < N_NODES) ? node : (N_NODES - 1);
        const uint32 o0 = off[nn];
        const uint32 o1 = off[nn + 1];
        oo[pr2] = o0;
        dd[pr2] = (node < N_NODES) ? (o1 - o0) : 0u;
    }
    // ---- hoisted round-0 AND round-1 index loads: 32 independent ----
    uint32 sx[4][4], sy[4][4];
#pragma unroll
    for (int pr2 = 0; pr2 < 4; ++pr2) {
        const uint32 d0 = dd[pr2];
        const uint32 dm = d0 ? d0 - 1u : 0u;
        const uint32* sp = sorted_src + oo[pr2];
#pragma unroll
        for (int k = 0; k < 4; ++k) {
            uint32 i0 = 2u * (uint32)k + (uint32)sub;
            uint32 i1 = 8u + 2u * (uint32)k + (uint32)sub;
            sx[pr2][k] = sp[i0 < dm ? i0 : dm];
            sy[pr2][k] = sp[i1 < dm ? i1 : dm];
        }
    }
    // bound indices (row 0 for out-of-range slots -> safe addresses)
#pragma unroll
    for (int pr2 = 0; pr2 < 4; ++pr2)
#pragma unroll
        for (int k = 0; k < 4; ++k) {
            if (2u * (uint32)k + (uint32)sub >= dd[pr2]) sx[pr2][k] = 0u;
            if (8u + 2u * (uint32)k + (uint32)sub >= dd[pr2]) sy[pr2][k] = 0u;
        }

    // ---- issue all round-0 row loads (16 in flight) ----
    uint4 u[4][4];
#pragma unroll
    for (int pr2 = 0; pr2 < 4; ++pr2)
#pragma unroll
        for (int k = 0; k < 4; ++k) u[pr2][k] = LD(sx[pr2][k]);

    // ---- issue round-1 row loads only for deep (d>8) groups ----
    uint4 v[4][4];
#pragma unroll
    for (int pr2 = 0; pr2 < 4; ++pr2) {
        if (dd[pr2] > 8u) {
#pragma unroll
            for (int k = 0; k < 4; ++k) v[pr2][k] = LD(sy[pr2][k]);
        } else {
#pragma unroll
            for (int k = 0; k < 4; ++k) v[pr2][k] = make_uint4(0u, 0u, 0u, 0u);
        }
    }

    // ---- accumulate per pair ----
#pragma unroll
    for (int pr2 = 0; pr2 < 4; ++pr2) {
        const uint32 d0 = dd[pr2];
        float aA[8] = {0.f,0.f,0.f,0.f,0.f,0.f,0.f,0.f};
        float aB[8] = {0.f,0.f,0.f,0.f,0.f,0.f,0.f,0.f};
#pragma unroll
        for (int k = 0; k < 4; ++k) {
            if (2u * (uint32)k + (uint32)sub >= d0) u[pr2][k] = make_uint4(0u,0u,0u,0u);
            if (8u + 2u * (uint32)k + (uint32)sub >= d0) v[pr2][k] = make_uint4(0u,0u,0u,0u);
        }
        ACC(aA, u[pr2][0]); ACC(aB, u[pr2][1]); ACC(aA, u[pr2][2]); ACC(aB, u[pr2][3]);
        ACC(aA, v[pr2][0]); ACC(aB, v[pr2][1]); ACC(aA, v[pr2][2]); ACC(aB, v[pr2][3]);

        // j >= 16: very rare (P ~ 2e-4 per node)
        const uint32* sp = sorted_src + oo[pr2];
        uint32 j = 16;
        for (; j + 8 <= d0; j += 8) {
            uint32 s0 = sp[j + 0 + sub];
            uint32 s1 = sp[j + 2 + sub];
            uint32 s2 = sp[j + 4 + sub];
            uint32 s3 = sp[j + 6 + sub];
            uint4 w0 = LD(s0); uint4 w1 = LD(s1); uint4 w2 = LD(s2); uint4 w3 = LD(s3);
            ACC(aA, w0); ACC(aB, w1); ACC(aA, w2); ACC(aB, w3);
        }
        if (j < d0) {
            const uint32 dm1 = d0 - 1;
            uint32 i0 = j + 0 + sub, i1 = j + 2 + sub, i2 = j + 4 + sub, i3 = j + 6 + sub;
            uint32 s0 = sp[i0 < dm1 ? i0 : dm1];
            uint32 s1 = sp[i1 < dm1 ? i1 : dm1];
            uint32 s2 = sp[i2 < dm1 ? i2 : dm1];
            uint32 s3 = sp[i3 < dm1 ? i3 : dm1];
            uint4 w0 = LD(s0); uint4 w1 = LD(s1); uint4 w2 = LD(s2); uint4 w3 = LD(s3);
            if (i0 >= d0) w0 = make_uint4(0u,0u,0u,0u);
            if (i1 >= d0) w1 = make_uint4(0u,0u,0u,0u);
            if (i2 >= d0) w2 = make_uint4(0u,0u,0u,0u);
            if (i3 >= d0) w3 = make_uint4(0u,0u,0u,0u);
            ACC(aA, w0); ACC(aB, w1); ACC(aA, w2); ACC(aB, w3);
        }
#pragma unroll
        for (int r = 0; r < 8; ++r) {
            aA[r] += aB[r];
            aA[r] += __shfl_xor(aA[r], 16);     // sub0 + sub1
        }
        if (sub == 0) {
            const int nl = wave * 8 + pr2 * 2 + g;
            const float inv = 1.0f / (float)(dd[pr2] > 0u ? dd[pr2] : 1u);
            uint4 w;
            w.x = f2bf(aA[0] * inv) | (f2bf(aA[1] * inv) << 16);
            w.y = f2bf(aA[2] * inv) | (f2bf(aA[3] * inv) << 16);
            w.z = f2bf(aA[4] * inv) | (f2bf(aA[5] * inv) << 16);
            w.w = f2bf(aA[6] * inv) | (f2bf(aA[7] * inv) << 16);
            *reinterpret_cast<uint4*>(&Am[nl * 128 + ((cl ^ (nl & 7)) * 8)]) = w;
        }
    }
#undef LD
#undef ACC
    __syncthreads();

    // ---- GEMM phase: wave = 16 rows x 64 cols (rg = wave>>1, chh = wave&1) ----
    const int rg  = wave >> 1;
    const int chh = wave & 1;
    const int lr  = lane & 15;
    const int lkq = lane >> 4;                  // 0..3
    const int lk  = lkq * 8;
    const int arow = rg * 16 + lr;              // local row

    f32x4 gac[4];
#pragma unroll
    for (int n = 0; n < 4; ++n) gac[n] = (f32x4){0.f, 0.f, 0.f, 0.f};

    // mean half (ks 0..3) from LDS, swizzled
#pragma unroll
    for (int ks = 0; ks < 4; ++ks) {
        const int c0 = lkq + ks * 4;
        short8 a = *reinterpret_cast<const short8*>(
            &Am[arow * 128 + ((c0 ^ (arow & 7)) * 8)]);
#pragma unroll
        for (int n = 0; n < 4; ++n) {
            short8 b = *reinterpret_cast<const short8*>(
                &WcL[((chh * 32 + n * 8 + ks) * 64 + lane) * 8]);
            gac[n] = __builtin_amdgcn_mfma_f32_16x16x32_bf16(a, b, gac[n], 0, 0, 0);
        }
    }
    // nf half (ks 4..7) from global compact AbufN
    const unsigned short* pa = AbufN + (size_t)(row0 + arow) * 128 + lk;
#pragma unroll
    for (int ks = 4; ks < 8; ++ks) {
        short8 a = *reinterpret_cast<const short8*>(pa + (ks - 4) * 32);
#pragma unroll
        for (int n = 0; n < 4; ++n) {
            short8 b = *reinterpret_cast<const short8*>(
                &WcL[((chh * 32 + n * 8 + ks) * 64 + lane) * 8]);
            gac[n] = __builtin_amdgcn_mfma_f32_16x16x32_bf16(a, b, gac[n], 0, 0, 0);
        }
    }

    // epilogue (C/D: col = lane&15, row = (lane>>4)*4 + reg)
    float bv[4];
#pragma unroll
    for (int n = 0; n < 4; ++n) bv[n] = biasc[chh * 64 + n * 16 + lr];

    const int rq = lkq * 4;
#pragma unroll
    for (int r = 0; r < 4; ++r) {
        const int row = row0 + rg * 16 + rq + r;
        if (row < N_NODES) {
            float* orow = out + (size_t)row * D + chh * 64;
#pragma unroll
            for (int n = 0; n < 4; ++n)
                orow[n * 16 + lr] = gac[n][r] + bv[n];
        }
    }
}

extern "C" void kernel_launch(void* const* d_in, const int* in_sizes, int n_in,
                              void* d_out, int out_size, void* d_ws, size_t ws_size,
                              hipStream_t stream) {
    const float* nf    = (const float*)d_in[0];
    const int*   edges = (const int*)d_in[1];
    const float* Wl    = (const float*)d_in[2];
    const float* bl    = (const float*)d_in[3];
    const float* Ws    = (const float*)d_in[4];
    const float* bs    = (const float*)d_in[5];
    float* out = (float*)d_out;

    // workspace layout
    char* p = (char*)d_ws;
    unsigned short* AbufN = (unsigned short*)p; p += (size_t)M_PAD * 128 * sizeof(unsigned short);
    uint32* cntmat     = (uint32*)p; p += (size_t)(SCAN_N + 64) * sizeof(uint32);
    uint32* bpair      = (uint32*)p; p += (size_t)N_EDGES * sizeof(uint32);
    uint32* sorted_src = (uint32*)p; p += (size_t)N_EDGES * sizeof(uint32);
    uint32* off        = (uint32*)p; p += (size_t)(N_NODES + 8) * sizeof(uint32);
    uint64* flags      = (uint64*)p; p += 2048;
    unsigned short* WcF = (unsigned short*)p; p += (size_t)D * 256 * sizeof(unsigned short);
    float* biasc       = (float*)p;

    k1_convert_count<<<1024, 256, 0, stream>>>(nf, AbufN, edges, cntmat, flags);
    k2_scan<<<SCAN_BLK, 256, 0, stream>>>(cntmat, flags, Wl, Ws, bl, bs, WcF, biasc);
    k3_bucket<<<NCH, 256, 0, stream>>>(edges, cntmat, bpair);
    k4_csr<<<NB, 256, 0, stream>>>(bpair, cntmat, off, sorted_src);
    k_fused<<<(N_NODES + 63) / 64, 512, 0, stream>>>(AbufN, off, sorted_src, WcF, biasc, out);
}

// Round 19
// 87.406 us; speedup vs baseline: 1.2025x; 1.2025x over previous
//
#include <hip/hip_runtime.h>

#define N_NODES 100000
#define N_EDGES 600000
#define D 128
#define M_PAD 100096            // allocation pad for AbufN rows

#define NB   196                // buckets = tgt >> 9
#define BWID 512                // nodes per bucket
#define NCH  196                // edge chunks
#define CE   3062               // edges per chunk (last: 2910)
#define SCAN_N (NB * NCH)       // 38416
#define SCAN_BLK 151            // ceil(SCAN_N / 256)

typedef unsigned int uint32;
typedef unsigned long long uint64;
typedef __attribute__((ext_vector_type(8))) short short8;
typedef __attribute__((ext_vector_type(4))) float f32x4;

__device__ __forceinline__ uint32 f2bf(float x) {          // RNE f32 -> bf16
    uint32 u = __float_as_uint(x);
    return (u + 0x7FFFu + ((u >> 16) & 1u)) >> 16;
}
__device__ __forceinline__ float bflo(uint32 u) { return __uint_as_float(u << 16); }
__device__ __forceinline__ float bfhi(uint32 u) { return __uint_as_float(u & 0xFFFF0000u); }

// ---------------------------------------------------------------------------
// K1: convert nf -> bf16 compact AbufN[r][128] (grid-stride, 1024 blocks);
// blocks 0..195 also count their edge-chunk's bucket histogram in LDS.
// Block 1023 zeroes the scan flags.
// ---------------------------------------------------------------------------
__global__ __launch_bounds__(256) void k1_convert_count(
        const float* __restrict__ nf, unsigned short* __restrict__ AbufN,
        const int* __restrict__ edges, uint32* __restrict__ cntmat,
        uint64* __restrict__ flags) {
    __shared__ uint32 c[NB];
    const int tid = threadIdx.x;
    const int bid = blockIdx.x;

    if (bid == 1023 && tid < SCAN_BLK) flags[tid] = 0ULL;

    for (int idx = bid * 256 + tid; idx < N_NODES * 16; idx += 1024 * 256) {
        int r = idx >> 4;
        int ccol = (idx & 15) * 8;
        const float4 v0 = *reinterpret_cast<const float4*>(nf + (size_t)r * D + ccol);
        const float4 v1 = *reinterpret_cast<const float4*>(nf + (size_t)r * D + ccol + 4);
        uint4 w;
        w.x = f2bf(v0.x) | (f2bf(v0.y) << 16);
        w.y = f2bf(v0.z) | (f2bf(v0.w) << 16);
        w.z = f2bf(v1.x) | (f2bf(v1.y) << 16);
        w.w = f2bf(v1.z) | (f2bf(v1.w) << 16);
        *reinterpret_cast<uint4*>(AbufN + (size_t)r * 128 + ccol) = w;
    }

    if (bid < NCH) {
        for (int i = tid; i < NB; i += 256) c[i] = 0u;
        __syncthreads();
        const int e0 = bid * CE;
        const int e1 = (e0 + CE < N_EDGES) ? e0 + CE : N_EDGES;
        for (int e = e0 + tid; e < e1; e += 256) {
            int tgt = edges[N_EDGES + e];
            atomicAdd(&c[tgt >> 9], 1u);               // LDS atomic
        }
        __syncthreads();
        for (int i = tid; i < NB; i += 256)
            cntmat[(size_t)i * NCH + bid] = c[i];      // bucket-major
    }
}

// ---------------------------------------------------------------------------
// K2: publish/poll exclusive scan over cntmat (38416 elems, 151 blocks),
// in-place counts -> bases. Idle width does W-prep + bias fuse.
// ---------------------------------------------------------------------------
__global__ __launch_bounds__(256) void k2_scan(
        uint32* __restrict__ cntmat, uint64* __restrict__ flags,
        const float* __restrict__ Wl, const float* __restrict__ Ws,
        const float* __restrict__ bl, const float* __restrict__ bs,
        unsigned short* __restrict__ WcF, float* __restrict__ biasc) {
    const int gidx = blockIdx.x * 256 + threadIdx.x;
    if (gidx < 4096) {
        int lane = gidx & 63, f2 = gidx >> 6;
        int ks = f2 & 7, nn = (f2 >> 3) & 3, ch = f2 >> 5;
        int j = ch * 64 + nn * 16 + (lane & 15);
        int kb = ks * 32 + (lane >> 4) * 8;
        const float* srcp = (kb < D) ? (Wl + (size_t)j * D + kb)
                                     : (Ws + (size_t)j * D + (kb - D));
        const float4 v0 = *reinterpret_cast<const float4*>(srcp);
        const float4 v1 = *reinterpret_cast<const float4*>(srcp + 4);
        uint4 w;
        w.x = f2bf(v0.x) | (f2bf(v0.y) << 16);
        w.y = f2bf(v0.z) | (f2bf(v0.w) << 16);
        w.z = f2bf(v1.x) | (f2bf(v1.y) << 16);
        w.w = f2bf(v1.z) | (f2bf(v1.w) << 16);
        *reinterpret_cast<uint4*>(WcF + (size_t)gidx * 8) = w;
    }
    if (gidx < D) biasc[gidx] = bl[gidx] + bs[gidx];

    __shared__ uint32 s[256];
    __shared__ uint32 r2[256];
    const int t = threadIdx.x;
    const int b = blockIdx.x;
    const int i = b * 256 + t;
    const uint32 v = (i < SCAN_N) ? cntmat[i] : 0u;
    s[t] = v;
    __syncthreads();
    for (int d = 1; d < 256; d <<= 1) {
        uint32 add = (t >= d) ? s[t - d] : 0u;
        __syncthreads();
        s[t] += add;
        __syncthreads();
    }
    const uint32 incl = s[t];
    const uint32 total = s[255];
    if (t == 0) atomicExch(&flags[b], (1ULL << 32) | (uint64)total);
    uint32 agg = 0;
    if (t < b) {                                       // b <= 150 < 256
        uint64 fv;
        do { fv = atomicAdd(&flags[t], 0ULL); } while ((fv >> 32) == 0ULL);
        agg = (uint32)fv;
    }
    r2[t] = agg;
    __syncthreads();
    for (int d2 = 128; d2 > 0; d2 >>= 1) {
        if (t < d2) r2[t] += r2[t + d2];
        __syncthreads();
    }
    if (i < SCAN_N) cntmat[i] = r2[0] + incl - v;      // exclusive base, in place
}

// ---------------------------------------------------------------------------
// K3: scatter edges into bucket-grouped PACKED array ((tgt&511)<<17 | src).
// Rank via LDS atomic return + disjoint (bucket,chunk) bases -> no g-atomics.
// ---------------------------------------------------------------------------
__global__ __launch_bounds__(256) void k3_bucket(
        const int* __restrict__ edges, const uint32* __restrict__ base,
        uint32* __restrict__ bpair) {
    __shared__ uint32 c[NB];
    __shared__ uint32 bb[NB];
    const int t = threadIdx.x;
    const int cid = blockIdx.x;
    for (int i = t; i < NB; i += 256) {
        c[i] = 0u;
        bb[i] = base[(size_t)i * NCH + cid];
    }
    __syncthreads();
    const int e0 = cid * CE;
    const int e1 = (e0 + CE < N_EDGES) ? e0 + CE : N_EDGES;
    for (int e = e0 + t; e < e1; e += 256) {
        uint32 src = (uint32)edges[e];
        uint32 tgt = (uint32)edges[N_EDGES + e];
        uint32 bkt = tgt >> 9;
        uint32 r = atomicAdd(&c[bkt], 1u);             // LDS atomic
        bpair[bb[bkt] + r] = ((tgt & 511u) << 17) | src;
    }
}

// ---------------------------------------------------------------------------
// K4: one block per bucket. LDS 512-counter histogram -> local exclusive
// scan -> off[] (+ sentinel) and sorted_src (L2-local windows).
// ---------------------------------------------------------------------------
__global__ __launch_bounds__(256) void k4_csr(
        const uint32* __restrict__ bpair, const uint32* __restrict__ base,
        uint32* __restrict__ off, uint32* __restrict__ sorted_src) {
    __shared__ uint32 h[BWID];
    __shared__ uint32 h2[BWID];
    __shared__ uint32 pr[256];
    const int t = threadIdx.x;
    const int b = blockIdx.x;
    const uint32 start = base[(size_t)b * NCH];
    const uint32 end = (b == NB - 1) ? N_EDGES : base[(size_t)(b + 1) * NCH];
    for (int i = t; i < BWID; i += 256) { h[i] = 0u; h2[i] = 0u; }
    __syncthreads();
    for (uint32 e = start + t; e < end; e += 256) {
        atomicAdd(&h[bpair[e] >> 17], 1u);             // LDS atomic
    }
    __syncthreads();
    const uint32 e0c = h[2 * t];
    const uint32 e1c = h[2 * t + 1];
    pr[t] = e0c + e1c;
    __syncthreads();
    for (int d = 1; d < 256; d <<= 1) {
        uint32 add = (t >= d) ? pr[t - d] : 0u;
        __syncthreads();
        pr[t] += add;
        __syncthreads();
    }
    const uint32 exb = (t > 0) ? pr[t - 1] : 0u;
    const int node0 = b * BWID + 2 * t;
    if (node0 < N_NODES) off[node0] = start + exb;
    if (node0 + 1 < N_NODES) off[node0 + 1] = start + exb + e0c;
    if (b == NB - 1 && t == 0) off[N_NODES] = N_EDGES;  // sentinel
    h[2 * t] = exb;
    h[2 * t + 1] = exb + e0c;
    __syncthreads();
    for (uint32 e = start + t; e < end; e += 256) {
        uint32 pq = bpair[e];
        uint32 lt = pq >> 17;
        uint32 r = atomicAdd(&h2[lt], 1u);              // LDS atomic
        sorted_src[start + h[lt] + r] = pq & 0x1FFFFu;
    }
}

// ---------------------------------------------------------------------------
// K5 fused gather + MFMA GEMM (verified best, R14). Block = 64 rows x 128
// cols, 512 threads, WcL (64 KB) + Am (16 KB) LDS. Gather: hoisted off +
// first-round indices; row loads in 2 groups of 8; per-pair serial
// leftovers (rare). Mean -> swizzled LDS only. MFMA from LDS + AbufN.
// ---------------------------------------------------------------------------
__global__ __launch_bounds__(512) void k_fused(
        const unsigned short* __restrict__ AbufN,
        const uint32* __restrict__ off,
        const uint32* __restrict__ sorted_src,
        const unsigned short* __restrict__ WcF,
        const float* __restrict__ biasc,
        float* __restrict__ out) {
    __shared__ unsigned short WcL[32768];       // 64 KB
    __shared__ unsigned short Am[8192];         // 16 KB: 64 x 128 bf16 (swizzled)
    const int tid = threadIdx.x;
    const int wave = tid >> 6;                  // 0..7
    const int lane = tid & 63;
    const int row0 = blockIdx.x * 64;

    // stage all W fragments (linear copy; overlaps with gather loads)
#pragma unroll
    for (int i = 0; i < 8; ++i) {
        const int o = (i * 512 + tid) * 8;
        *reinterpret_cast<short8*>(&WcL[o]) = *reinterpret_cast<const short8*>(WcF + o);
    }

    const int sub = (lane >> 4) & 1;            // edge parity
    const int cl  = lane & 15;                  // 16B column chunk
    const int g   = lane >> 5;                  // node within pair

#define LD(s) (*reinterpret_cast<const uint4*>(AbufN + (size_t)(s) * 128 + cl * 8))
#define ACC(a, u) { a[0] += bflo(u.x); a[1] += bfhi(u.x); a[2] += bflo(u.y); a[3] += bfhi(u.y); \
                    a[4] += bflo(u.z); a[5] += bfhi(u.z); a[6] += bflo(u.w); a[7] += bfhi(u.w); }

    // ---- hoisted off/deg loads: 4 pairs, 8 independent loads ----
    uint32 oo[4], dd[4];
#pragma unroll
    for (int pr2 = 0; pr2 < 4; ++pr2) {
        const int nl = wave * 8 + pr2 * 2 + g;
        const int node = row0 + nl;
        const int nn = (node < N_NODES) ? node : (N_NODES - 1);
        const uint32 o0 = off[nn];
        const uint32 o1 = off[nn + 1];
        oo[pr2] = o0;
        dd[pr2] = (node < N_NODES) ? (o1 - o0) : 0u;
    }
    // ---- hoisted first-round index loads: 16 independent ----
    uint32 sx[4][4];
#pragma unroll
    for (int pr2 = 0; pr2 < 4; ++pr2) {
        const uint32 d0 = dd[pr2];
        const uint32 dm = d0 ? d0 - 1u : 0u;
        const uint32* sp = sorted_src + oo[pr2];
#pragma unroll
        for (int k = 0; k < 4; ++k) {
            uint32 i = 2u * (uint32)k + (uint32)sub;
            sx[pr2][k] = sp[i < dm ? i : dm];
        }
    }
#pragma unroll
    for (int pr2 = 0; pr2 < 4; ++pr2)
#pragma unroll
        for (int k = 0; k < 4; ++k)
            if (2u * (uint32)k + (uint32)sub >= dd[pr2]) sx[pr2][k] = 0u;  // bound rows

    // ---- row loads in 2 groups of 8; accumulate per pair ----
#pragma unroll
    for (int pg = 0; pg < 2; ++pg) {
        uint4 u[2][4];
#pragma unroll
        for (int pp = 0; pp < 2; ++pp) {
            const int pr2 = pg * 2 + pp;
#pragma unroll
            for (int k = 0; k < 4; ++k) u[pp][k] = LD(sx[pr2][k]);
        }
#pragma unroll
        for (int pp = 0; pp < 2; ++pp) {
            const int pr2 = pg * 2 + pp;
            const uint32 d0 = dd[pr2];
            float aA[8] = {0.f,0.f,0.f,0.f,0.f,0.f,0.f,0.f};
            float aB[8] = {0.f,0.f,0.f,0.f,0.f,0.f,0.f,0.f};
#pragma unroll
            for (int k = 0; k < 4; ++k)
                if (2u * (uint32)k + (uint32)sub >= d0) u[pp][k] = make_uint4(0u,0u,0u,0u);
            ACC(aA, u[pp][0]); ACC(aB, u[pp][1]); ACC(aA, u[pp][2]); ACC(aB, u[pp][3]);

            // leftovers (d > 8): rare (~15% of nodes)
            const uint32* sp = sorted_src + oo[pr2];
            uint32 j = 8;
            for (; j + 8 <= d0; j += 8) {
                uint32 s0 = sp[j + 0 + sub];
                uint32 s1 = sp[j + 2 + sub];
                uint32 s2 = sp[j + 4 + sub];
                uint32 s3 = sp[j + 6 + sub];
                uint4 v0 = LD(s0); uint4 v1 = LD(s1); uint4 v2 = LD(s2); uint4 v3 = LD(s3);
                ACC(aA, v0); ACC(aB, v1); ACC(aA, v2); ACC(aB, v3);
            }
            if (j < d0) {
                const uint32 dm1 = d0 - 1;
                uint32 i0 = j + 0 + sub, i1 = j + 2 + sub, i2 = j + 4 + sub, i3 = j + 6 + sub;
                uint32 s0 = sp[i0 < dm1 ? i0 : dm1];
                uint32 s1 = sp[i1 < dm1 ? i1 : dm1];
                uint32 s2 = sp[i2 < dm1 ? i2 : dm1];
                uint32 s3 = sp[i3 < dm1 ? i3 : dm1];
                uint4 v0 = LD(s0); uint4 v1 = LD(s1); uint4 v2 = LD(s2); uint4 v3 = LD(s3);
                if (i0 >= d0) v0 = make_uint4(0u,0u,0u,0u);
                if (i1 >= d0) v1 = make_uint4(0u,0u,0u,0u);
                if (i2 >= d0) v2 = make_uint4(0u,0u,0u,0u);
                if (i3 >= d0) v3 = make_uint4(0u,0u,0u,0u);
                ACC(aA, v0); ACC(aB, v1); ACC(aA, v2); ACC(aB, v3);
            }
#pragma unroll
            for (int r = 0; r < 8; ++r) {
                aA[r] += aB[r];
                aA[r] += __shfl_xor(aA[r], 16);     // sub0 + sub1
            }
            if (sub == 0) {
                const int nl = wave * 8 + pr2 * 2 + g;
                const float inv = 1.0f / (float)(dd[pr2] > 0u ? dd[pr2] : 1u);
                uint4 w;
                w.x = f2bf(aA[0] * inv) | (f2bf(aA[1] * inv) << 16);
                w.y = f2bf(aA[2] * inv) | (f2bf(aA[3] * inv) << 16);
                w.z = f2bf(aA[4] * inv) | (f2bf(aA[5] * inv) << 16);
                w.w = f2bf(aA[6] * inv) | (f2bf(aA[7] * inv) << 16);
                *reinterpret_cast<uint4*>(&Am[nl * 128 + ((cl ^ (nl & 7)) * 8)]) = w;
            }
        }
    }
#undef LD
#undef ACC
    __syncthreads();

    // ---- GEMM phase: wave = 16 rows x 64 cols (rg = wave>>1, chh = wave&1) ----
    const int rg  = wave >> 1;
    const int chh = wave & 1;
    const int lr  = lane & 15;
    const int lkq = lane >> 4;                  // 0..3
    const int lk  = lkq * 8;
    const int arow = rg * 16 + lr;              // local row

    f32x4 gac[4];
#pragma unroll
    for (int n = 0; n < 4; ++n) gac[n] = (f32x4){0.f, 0.f, 0.f, 0.f};

    // mean half (ks 0..3) from LDS, swizzled
#pragma unroll
    for (int ks = 0; ks < 4; ++ks) {
        const int c0 = lkq + ks * 4;
        short8 a = *reinterpret_cast<const short8*>(
            &Am[arow * 128 + ((c0 ^ (arow & 7)) * 8)]);
#pragma unroll
        for (int n = 0; n < 4; ++n) {
            short8 b = *reinterpret_cast<const short8*>(
                &WcL[((chh * 32 + n * 8 + ks) * 64 + lane) * 8]);
            gac[n] = __builtin_amdgcn_mfma_f32_16x16x32_bf16(a, b, gac[n], 0, 0, 0);
        }
    }
    // nf half (ks 4..7) from global compact AbufN
    const unsigned short* pa = AbufN + (size_t)(row0 + arow) * 128 + lk;
#pragma unroll
    for (int ks = 4; ks < 8; ++ks) {
        short8 a = *reinterpret_cast<const short8*>(pa + (ks - 4) * 32);
#pragma unroll
        for (int n = 0; n < 4; ++n) {
            short8 b = *reinterpret_cast<const short8*>(
                &WcL[((chh * 32 + n * 8 + ks) * 64 + lane) * 8]);
            gac[n] = __builtin_amdgcn_mfma_f32_16x16x32_bf16(a, b, gac[n], 0, 0, 0);
        }
    }

    // epilogue (C/D: col = lane&15, row = (lane>>4)*4 + reg)
    float bv[4];
#pragma unroll
    for (int n = 0; n < 4; ++n) bv[n] = biasc[chh * 64 + n * 16 + lr];

    const int rq = lkq * 4;
#pragma unroll
    for (int r = 0; r < 4; ++r) {
        const int row = row0 + rg * 16 + rq + r;
        if (row < N_NODES) {
            float* orow = out + (size_t)row * D + chh * 64;
#pragma unroll
            for (int n = 0; n < 4; ++n)
                orow[n * 16 + lr] = gac[n][r] + bv[n];
        }
    }
}

extern "C" void kernel_launch(void* const* d_in, const int* in_sizes, int n_in,
                              void* d_out, int out_size, void* d_ws, size_t ws_size,
                              hipStream_t stream) {
    const float* nf    = (const float*)d_in[0];
    const int*   edges = (const int*)d_in[1];
    const float* Wl    = (const float*)d_in[2];
    const float* bl    = (const float*)d_in[3];
    const float* Ws    = (const float*)d_in[4];
    const float* bs    = (const float*)d_in[5];
    float* out = (float*)d_out;

    // workspace layout
    char* p = (char*)d_ws;
    unsigned short* AbufN = (unsigned short*)p; p += (size_t)M_PAD * 128 * sizeof(unsigned short);
    uint32* cntmat     = (uint32*)p; p += (size_t)(SCAN_N + 64) * sizeof(uint32);
    uint32* bpair      = (uint32*)p; p += (size_t)N_EDGES * sizeof(uint32);
    uint32* sorted_src = (uint32*)p; p += (size_t)N_EDGES * sizeof(uint32);
    uint32* off        = (uint32*)p; p += (size_t)(N_NODES + 8) * sizeof(uint32);
    uint64* flags      = (uint64*)p; p += 2048;
    unsigned short* WcF = (unsigned short*)p; p += (size_t)D * 256 * sizeof(unsigned short);
    float* biasc       = (float*)p;

    k1_convert_count<<<1024, 256, 0, stream>>>(nf, AbufN, edges, cntmat, flags);
    k2_scan<<<SCAN_BLK, 256, 0, stream>>>(cntmat, flags, Wl, Ws, bl, bs, WcF, biasc);
    k3_bucket<<<NCH, 256, 0, stream>>>(edges, cntmat, bpair);
    k4_csr<<<NB, 256, 0, stream>>>(bpair, cntmat, off, sorted_src);
    k_fused<<<(N_NODES + 63) / 64, 512, 0, stream>>>(AbufN, off, sorted_src, WcF, biasc, out);
}